// Round 13
// baseline (370.299 us; speedup 1.0000x reference)
//
#include <hip/hip_runtime.h>
#include <stdint.h>

#define N_IMGS 8
#define NLVL 5
#define TOT 392832          // total anchors across levels
#define PRE_K 1000
#define POST_K 1000
#define KSEL 5000           // 5 levels * 1000
#define MASKW 79            // ceil(5000/64)
#define MROWS 5056          // KSEL padded to 79 full 64-row chunks
#define NCHUNK 79
#define LPAD 1024           // per-level padded list length
#define MSLOTS (NLVL * LPAD)

typedef unsigned long long u64;

struct Ptrs {
    const float* obj[5];
    const float* del[5];
    const float* anch;
};

__device__ __forceinline__ unsigned flipf(float f) {
    unsigned u = __float_as_uint(f);
    return (u & 0x80000000u) ? ~u : (u | 0x80000000u);
}

__device__ __forceinline__ void lvl_info(int t, int& l, int& off, int& W, int& H) {
    if (t < 294912)      { l = 0; off = 0;      W = 384; H = 256; }
    else if (t < 368640) { l = 1; off = 294912; W = 192; H = 128; }
    else if (t < 387072) { l = 2; off = 368640; W = 96;  H = 64;  }
    else if (t < 391680) { l = 3; off = 387072; W = 48;  H = 32;  }
    else                 { l = 4; off = 391680; W = 24;  H = 16;  }
}

// Decode one proposal exactly as the reference (f32, no FMA contraction).
__device__ void decode_one(const Ptrs& P, int n, int t, float bx[4], bool& valid, int& lvl) {
#pragma clang fp contract(off)
    int l, off, W, H;
    lvl_info(t, l, off, W, H);
    lvl = l;
    int i = t - off;
    int a = i % 3;
    int p = i / 3;
    int y = p / W, x = p - y * W;
    const float* D = P.del[l];
    size_t plane = (size_t)W * H;
    size_t base = ((size_t)n * 12 + (size_t)a * 4) * plane + (size_t)y * W + x;
    float dx = D[base];
    float dy = D[base + plane];
    float dw = D[base + 2 * plane];
    float dh = D[base + 3 * plane];
    const float* an = P.anch + (size_t)t * 4;
    float a0 = an[0], a1 = an[1], a2 = an[2], a3 = an[3];
    float wa = a2 - a0, ha = a3 - a1;
    float cxa = a0 + 0.5f * wa, cya = a1 + 0.5f * ha;
    const float CLIP = 4.135166556742356f;  // log(1000/16) rounded to f32
    dw = fminf(dw, CLIP);
    dh = fminf(dh, CLIP);
    float cx = dx * wa + cxa;
    float cy = dy * ha + cya;
    float pw = expf(dw) * wa;
    float ph = expf(dh) * ha;
    float x1 = cx - 0.5f * pw, y1 = cy - 0.5f * ph;
    float x2 = cx + 0.5f * pw, y2 = cy + 0.5f * ph;
    x1 = fminf(fmaxf(x1, 0.f), 1536.f);
    x2 = fminf(fmaxf(x2, 0.f), 1536.f);
    y1 = fminf(fmaxf(y1, 0.f), 1024.f);
    y2 = fminf(fmaxf(y2, 0.f), 1024.f);
    bx[0] = x1; bx[1] = y1; bx[2] = x2; bx[3] = y2;
    valid = ((x2 - x1) >= 1e-3f) && ((y2 - y1) >= 1e-3f);
}

__global__ void k_zero_out(float* out, int n) {
    int i = blockIdx.x * blockDim.x + threadIdx.x;
    if (i < n) out[i] = 0.f;
}

// Flatten objectness into (h,w,a) order per level, store order-flipped bits.
// Also initializes vcnt (block 0) — must run before k_mergedec.
__global__ void k_scores(Ptrs P, unsigned* scores, int* vcnt) {
    if (blockIdx.x == 0 && threadIdx.x < N_IMGS) vcnt[threadIdx.x] = KSEL;
    int idx = blockIdx.x * blockDim.x + threadIdx.x;
    if (idx >= N_IMGS * TOT) return;
    int n = idx / TOT, t = idx - n * TOT;
    int l, off, W, H;
    lvl_info(t, l, off, W, H);
    int i = t - off;
    int a = i % 3;
    int p = i / 3;
    int y = p / W, x = p - y * W;
    const float* O = P.obj[l];
    float v = O[(((size_t)n * 3 + a) * H + y) * (size_t)W + x];
    scores[idx] = flipf(v);
}

// Exact top-1000 per (image, level), lax.top_k tie semantics (score desc, index asc).
#define HCOPY 4100          // 4096 bins + 4 pad (bank decorrelation between copies)
#define CANDMAX 4096
__global__ __launch_bounds__(1024) void k_select(const unsigned* scores, uint2* sel) {
    int task = blockIdx.x;
    int n = task / 5, l = task % 5;
    int off, len;
    switch (l) {
        case 0: off = 0;      len = 294912; break;
        case 1: off = 294912; len = 73728;  break;
        case 2: off = 368640; len = 18432;  break;
        case 3: off = 387072; len = 4608;   break;
        default: off = 391680; len = 1152;  break;
    }
    const unsigned* S = scores + (size_t)n * TOT + off;
    const uint4* S4 = (const uint4*)S;
    int len4 = len >> 2;
    int t = threadIdx.x;

    __shared__ __align__(16) char smem[2 * HCOPY * 4];   // hist, later reused as cand
    unsigned* hist = (unsigned*)smem;
    unsigned long long* cand = (unsigned long long*)smem;
    __shared__ unsigned suf[1024];
    __shared__ unsigned sh_pivot, sh_krem;
    __shared__ int sh_ngt, sh_nc;

    // zero both hist copies
    for (int i = t; i < 2 * HCOPY; i += 1024) hist[i] = 0u;
    __syncthreads();

    // 12-bit histogram, copy = t&1
    unsigned* myh = hist + (t & 1) * HCOPY;
    for (int i = t; i < len4; i += 1024) {
        uint4 v = S4[i];
        atomicAdd(&myh[v.x >> 20], 1u);
        atomicAdd(&myh[v.y >> 20], 1u);
        atomicAdd(&myh[v.z >> 20], 1u);
        atomicAdd(&myh[v.w >> 20], 1u);
    }
    __syncthreads();
    // reduce copies
    for (int i = t; i < 4096; i += 1024) hist[i] += hist[HCOPY + i];
    __syncthreads();
    // per-group sums (4 bins/thread), inclusive suffix scan
    suf[t] = hist[4 * t] + hist[4 * t + 1] + hist[4 * t + 2] + hist[4 * t + 3];
    for (int d = 1; d < 1024; d <<= 1) {
        __syncthreads();
        unsigned v = (t + d < 1024) ? suf[t + d] : 0u;
        __syncthreads();
        suf[t] += v;
    }
    __syncthreads();
    // boundary group: suf[t] >= K, suf[t+1] < K
    unsigned above = (t == 1023) ? 0u : suf[t + 1];
    if (suf[t] >= PRE_K && above < PRE_K) {
        int b = 4 * t + 3;
        unsigned c = above;
        while (c + hist[b] < PRE_K) { c += hist[b]; --b; }
        sh_pivot = (unsigned)b;
        sh_krem = PRE_K - c;          // how many to take from pivot bin
        sh_ngt = 0; sh_nc = 0;
    }
    __syncthreads();
    unsigned pivot = sh_pivot;
    int krem = (int)sh_krem;
    __syncthreads();   // hist no longer needed; smem becomes cand

    // compact pass
    uint2* out = sel + (size_t)task * PRE_K;
    for (int i = t; i < len4; i += 1024) {
        uint4 v4 = S4[i];
        unsigned vv[4] = {v4.x, v4.y, v4.z, v4.w};
#pragma unroll
        for (int q = 0; q < 4; ++q) {
            unsigned v = vv[q];
            unsigned b = v >> 20;
            if (b > pivot) {
                int slot = atomicAdd(&sh_ngt, 1);
                out[slot] = make_uint2(v, (unsigned)(off + 4 * i + q));
            } else if (b == pivot) {
                int c = atomicAdd(&sh_nc, 1);
                if (c < CANDMAX)
                    cand[c] = ((unsigned long long)v << 32) | (unsigned)(off + 4 * i + q);
            }
        }
    }
    __syncthreads();
    int C = min(sh_nc, CANDMAX);
    int nbase = sh_ngt;               // == PRE_K - krem
    // exact rank among pivot-bin candidates (uniform j-loop -> LDS broadcast reads)
    for (int i = t; i < C; i += 1024) {
        unsigned long long a = cand[i];
        unsigned vi = (unsigned)(a >> 32), xi = (unsigned)a;
        int rank = 0;
        for (int j = 0; j < C; ++j) {
            unsigned long long bj = cand[j];
            unsigned vj = (unsigned)(bj >> 32), xj = (unsigned)bj;
            rank += (vj > vi) || (vj == vi && xj < xi);
        }
        if (rank < krem) out[nbase + rank] = make_uint2(vi, xi);
    }
}

// Fused key-build + per-(image,level) bitonic sort of 1024-padded list.
// Key: ascending order == (score desc, concat position asc); invalid -> tail.
__global__ __launch_bounds__(1024) void k_sort1(Ptrs P, const uint2* sel, u64* keys2) {
    __shared__ u64 s[LPAD];
    int task = blockIdx.x;          // n*5 + l
    int n = task / 5;
    int t = threadIdx.x;
    u64 key = ~0ull;
    if (t < PRE_K) {
        uint2 sv = sel[(size_t)task * PRE_K + t];
        float bx[4]; bool valid; int lv;
        decode_one(P, n, (int)sv.y, bx, valid, lv);
        key = valid ? (((u64)(~sv.x) << 32) | (u64)sv.y)
                    : (0xFFFFFFFF00000000ull | (u64)sv.y);
    }
    s[t] = key;
    for (int k = 2; k <= LPAD; k <<= 1) {
        for (int j = k >> 1; j > 0; j >>= 1) {
            __syncthreads();
            int ixj = t ^ j;
            if (ixj > t) {
                u64 a = s[t], b = s[ixj];
                bool asc = ((t & k) == 0);
                if (asc ? (a > b) : (a < b)) { s[t] = b; s[ixj] = a; }
            }
        }
    }
    __syncthreads();
    keys2[(size_t)task * LPAD + t] = s[t];
}

// Fused stable 5-way merge-by-rank + decode + scatter. Rank = own position +
// per-other-list binary-search count (<= for lists with smaller index, < else).
// Real keys are unique and < pad ~0ull -> bijection onto ranks 0..4999.
__global__ void k_mergedec(Ptrs P, const u64* keys2,
                           float4* boxes, float4* nboxes, int* vcnt) {
    int idx = blockIdx.x * blockDim.x + threadIdx.x;
    if (idx >= N_IMGS * MSLOTS) return;
    int n = idx / MSLOTS, slot = idx - n * MSLOTS;
    int l = slot >> 10, p = slot & (LPAD - 1);
    const u64* base = keys2 + (size_t)n * MSLOTS;
    u64 key = base[(size_t)l * LPAD + p];
    if (key == ~0ull) return;       // pad slot
    int rank = p;
#pragma unroll
    for (int m = 0; m < NLVL; ++m) {
        if (m == l) continue;
        const u64* L = base + (size_t)m * LPAD;
        bool le = (m < l);
        int lo = 0, hi = LPAD;
        while (lo < hi) {
            int mid = (lo + hi) >> 1;
            u64 v = L[mid];
            bool take = le ? (v <= key) : (v < key);
            if (take) lo = mid + 1; else hi = mid;
        }
        rank += lo;
    }
    if (rank >= KSEL) return;       // safety (unreachable for real keys)
    int oidx = n * KSEL + rank;
    if ((key >> 32) == 0xFFFFFFFFull) {
        boxes[oidx] = make_float4(0.f, 0.f, 0.f, 0.f);
        nboxes[oidx] = make_float4(0.f, 0.f, 0.f, 0.f);
        atomicMin(&vcnt[n], rank);
        return;
    }
    int t = (int)(key & 0xFFFFFFFFull);
    float bx[4]; bool valid; int lv;
    decode_one(P, n, t, bx, valid, lv);
    boxes[oidx] = make_float4(bx[0], bx[1], bx[2], bx[3]);
    float offv = (float)lv * 1537.0f;   // (max(H,W)+1) * level
    nboxes[oidx] = make_float4(bx[0] + offv, bx[1] + offv, bx[2] + offv, bx[3] + offv);
}

// Suppression bitmask, ballot form. Lanes = cols (register-resident boxes),
// rounds = rows (readlane broadcast). Division eliminated on the common path
// via two-sided bracket (margin ~20 ulp provably brackets the rounded-division
// predicate since uni >= inter >= 0); ambiguous band falls back to the exact
// inter/uni > 0.7f (wave-level __any, ~never taken). Bit-exact vs reference.
// The ballot word w is wave-uniform, so "latch into lane rr" is a cndmask
// select (lane==rr ? w : acc) — no writelane needed.
// TRANSPOSED layout: maskT[(n*MASKW + cword)*MROWS + r]; upper blocks only.
__global__ __launch_bounds__(64) void k_mask(const float4* __restrict__ nboxes,
                                             u64* __restrict__ maskT) {
#pragma clang fp contract(off)
    int rb = blockIdx.x, cb = blockIdx.y, n = blockIdx.z;
    if (cb < rb) return;
    int lane = threadIdx.x;
    int r0 = rb * 64, c0 = cb * 64;
    const float4 z4 = make_float4(0.f, 0.f, 0.f, 0.f);
    float4 cbx = (c0 + lane < KSEL) ? nboxes[(size_t)n * KSEL + c0 + lane] : z4;
    float4 rbx = (r0 + lane < KSEL) ? nboxes[(size_t)n * KSEL + r0 + lane] : z4;
    float areaC = (cbx.z - cbx.x) * (cbx.w - cbx.y);
    float areaR = (rbx.z - rbx.x) * (rbx.w - rbx.y);
    u64 colmask = __ballot(c0 + lane < KSEL);
    bool diag = (rb == cb);
    u64 myword = 0ull;
    for (int rr = 0; rr < 64; ++rr) {
        float rx1 = __int_as_float(__builtin_amdgcn_readlane(__float_as_int(rbx.x), rr));
        float ry1 = __int_as_float(__builtin_amdgcn_readlane(__float_as_int(rbx.y), rr));
        float rx2 = __int_as_float(__builtin_amdgcn_readlane(__float_as_int(rbx.z), rr));
        float ry2 = __int_as_float(__builtin_amdgcn_readlane(__float_as_int(rbx.w), rr));
        float aR  = __int_as_float(__builtin_amdgcn_readlane(__float_as_int(areaR), rr));
        float ltx = fmaxf(rx1, cbx.x), lty = fmaxf(ry1, cbx.y);
        float rbxx = fminf(rx2, cbx.z), rbyy = fminf(ry2, cbx.w);
        float wv = fmaxf(rbxx - ltx, 0.f), hv = fmaxf(rbyy - lty, 0.f);
        float inter = wv * hv;
        float uni = (aR + areaC) - inter;
        float ta = 0.7f * uni;
        bool hi = inter > ta * 1.000002f;
        bool lo = inter < ta * 0.999998f;
        bool sup = hi;
        bool mid = !(hi || lo);
        if (__any((int)mid)) {
            float d = inter / uni;                 // exact reference path
            sup = mid ? (d > 0.7f) : sup;
        }
        if (diag) sup = sup && (lane > rr);
        u64 w = __ballot((int)sup) & colmask;      // wave-uniform
        myword = (lane == rr) ? w : myword;        // latch into owner lane
    }
    if (r0 + lane < KSEL)
        maskT[((size_t)n * MASKW + cb) * MROWS + r0 + lane] = myword;
}

__device__ __forceinline__ u64 bcast64(u64 v, int src) {
    unsigned lo = (unsigned)__builtin_amdgcn_readlane((int)(unsigned)v, src);
    unsigned hi = (unsigned)__builtin_amdgcn_readlane((int)(unsigned)(v >> 32), src);
    return ((u64)hi << 32) | (u64)lo;
}

// Wave64 OR-reduce via DPP (AMD GCN canonical sequence), result in lane 63.
__device__ __forceinline__ unsigned or_red_dpp(unsigned v) {
    v |= (unsigned)__builtin_amdgcn_update_dpp(0, (int)v, 0x111, 0xf, 0xf, true);  // row_shr:1
    v |= (unsigned)__builtin_amdgcn_update_dpp(0, (int)v, 0x112, 0xf, 0xf, true);  // row_shr:2
    v |= (unsigned)__builtin_amdgcn_update_dpp(0, (int)v, 0x114, 0xf, 0xf, true);  // row_shr:4
    v |= (unsigned)__builtin_amdgcn_update_dpp(0, (int)v, 0x118, 0xf, 0xf, true);  // row_shr:8
    v |= (unsigned)__builtin_amdgcn_update_dpp(0, (int)v, 0x142, 0xa, 0xf, false); // row_bcast:15
    v |= (unsigned)__builtin_amdgcn_update_dpp(0, (int)v, 0x143, 0xc, 0xf, false); // row_bcast:31
    return v;
}

// Single-wave greedy NMS scan, fully software-pipelined (see round 8 notes).
__global__ __launch_bounds__(64, 1) void k_scan(const u64* maskT, const int* vcnt,
                                                int* keep, int* nkept) {
    __shared__ int keep_lds[1024];
    int n = blockIdx.x, lane = threadIdx.x;
    int V = vcnt[n];
    const u64* MT = maskT + (size_t)n * MASKW * MROWS;

    for (int i = lane; i < 1024; i += 64) keep_lds[i] = 0;   // single wave: no barrier

    int cnt = 0, cntprev = 0;
    u64 keptprev = 0ull;
    bool full = false;
    int nchunks = (V + 63) >> 6;

    u64 bulk[16];
#pragma unroll
    for (int q = 0; q < 16; ++q) bulk[q] = 0ull;
    u64 wc = MT[lane];      // word 0 of chunk 0 rows
    u64 nc = 0ull;

    for (int c = 0; c < nchunks && !full; ++c) {
        // ---- assemble suppression word c from pipelined inputs ----
        u64 part = 0ull;
#pragma unroll
        for (int q = 0; q < 16; ++q)
            part |= (q * 64 + lane < cntprev) ? bulk[q] : 0ull;
        part |= ((keptprev >> lane) & 1ull) ? nc : 0ull;

        unsigned plo = or_red_dpp((unsigned)part);
        unsigned phi = or_red_dpp((unsigned)(part >> 32));
        u64 cur = ((u64)(unsigned)__builtin_amdgcn_readlane((int)phi, 63) << 32)
                | (u64)(unsigned)__builtin_amdgcn_readlane((int)plo, 63);

        // ---- issue generation c+1 ----
        int cntNow = cnt;
        int colN = (c + 1 < NCHUNK) ? (c + 1) : (NCHUNK - 1);
        const u64* colNp = MT + (size_t)colN * MROWS;
        {
            int kr[16];
#pragma unroll
            for (int q = 0; q < 16; ++q) kr[q] = keep_lds[q * 64 + lane];
#pragma unroll
            for (int q = 0; q < 16; ++q) bulk[q] = colNp[kr[q]];
        }
        u64 nc_next = colNp[(size_t)c * 64 + lane];
        u64 wc_next = colNp[(size_t)colN * 64 + lane];

        // ---- serial chain on chunk c ----
        int base = c * 64;
        int jmax = V - base; if (jmax > 64) jmax = 64;
        u64 avail = ~cur;
        if (jmax < 64) avail &= (1ull << jmax) - 1ull;
        while (avail) {
            int j = __builtin_ctzll(avail);
            if (lane == 0) keep_lds[cnt] = base + j;
            ++cnt;
            if (cnt == POST_K) { full = true; break; }
            u64 wcj = bcast64(wc, j);
            avail &= avail - 1;
            avail &= ~wcj;
        }
        keptprev = 0ull;
        for (int i = cntNow + (int)lane; i < cnt; i += 64) {
            int r = keep_lds[i];
            keptprev |= 1ull << (r - base);
        }
        {
            unsigned klo = or_red_dpp((unsigned)keptprev);
            unsigned khi = or_red_dpp((unsigned)(keptprev >> 32));
            keptprev = ((u64)(unsigned)__builtin_amdgcn_readlane((int)khi, 63) << 32)
                     | (u64)(unsigned)__builtin_amdgcn_readlane((int)klo, 63);
        }
        cntprev = cntNow;
        wc = wc_next;
        nc = nc_next;
    }

    for (int i = lane; i < cnt; i += 64) keep[n * POST_K + i] = keep_lds[i];
    if (lane == 0) nkept[n] = cnt;
}

__global__ void k_out(const float4* boxes, const int* keep, const int* nkept, float4* out) {
    int idx = blockIdx.x * blockDim.x + threadIdx.x;
    if (idx >= N_IMGS * POST_K) return;
    int n = idx / POST_K, k = idx - n * POST_K;
    float4 v = make_float4(0.f, 0.f, 0.f, 0.f);
    if (k < nkept[n]) v = boxes[(size_t)n * KSEL + keep[n * POST_K + k]];
    out[idx] = v;
}

extern "C" void kernel_launch(void* const* d_in, const int* in_sizes, int n_in,
                              void* d_out, int out_size, void* d_ws, size_t ws_size,
                              hipStream_t stream) {
    // dict order: obj0, delta0, obj1, delta1, ..., obj4, delta4, anchors
    Ptrs P;
    for (int l = 0; l < 5; ++l) {
        P.obj[l] = (const float*)d_in[2 * l];
        P.del[l] = (const float*)d_in[2 * l + 1];
    }
    P.anch = (const float*)d_in[10];

    // workspace carve
    size_t o = 0;
    auto alloc = [&](size_t bytes) {
        size_t cur = o;
        o = (o + bytes + 255) & ~(size_t)255;
        return cur;
    };
    size_t off_scores = alloc((size_t)N_IMGS * TOT * 4);
    size_t off_sel    = alloc((size_t)N_IMGS * KSEL * 8);
    size_t off_keys2  = alloc((size_t)N_IMGS * MSLOTS * 8);
    size_t off_boxes  = alloc((size_t)N_IMGS * KSEL * 16);
    size_t off_nbox   = alloc((size_t)N_IMGS * KSEL * 16);
    size_t off_mask   = alloc((size_t)N_IMGS * MASKW * MROWS * 8);
    size_t off_vcnt   = alloc(N_IMGS * 4);
    size_t off_keep   = alloc((size_t)N_IMGS * POST_K * 4);
    size_t off_nkept  = alloc(N_IMGS * 4);

    float* out = (float*)d_out;
    if (o > ws_size) {  // workspace too small: emit zeros (visible failure, no crash)
        k_zero_out<<<(out_size + 255) / 256, 256, 0, stream>>>(out, out_size);
        return;
    }

    char* w = (char*)d_ws;
    unsigned* scores = (unsigned*)(w + off_scores);
    uint2* sel       = (uint2*)(w + off_sel);
    u64* keys2       = (u64*)(w + off_keys2);
    float4* boxes    = (float4*)(w + off_boxes);
    float4* nboxes   = (float4*)(w + off_nbox);
    u64* maskT       = (u64*)(w + off_mask);
    int* vcnt        = (int*)(w + off_vcnt);
    int* keep        = (int*)(w + off_keep);
    int* nkept       = (int*)(w + off_nkept);

    k_scores<<<(N_IMGS * TOT + 255) / 256, 256, 0, stream>>>(P, scores, vcnt);
    k_select<<<N_IMGS * NLVL, 1024, 0, stream>>>(scores, sel);
    k_sort1<<<N_IMGS * NLVL, 1024, 0, stream>>>(P, sel, keys2);
    k_mergedec<<<(N_IMGS * MSLOTS + 255) / 256, 256, 0, stream>>>(P, keys2, boxes, nboxes, vcnt);
    k_mask<<<dim3(NCHUNK, MASKW, N_IMGS), 64, 0, stream>>>(nboxes, maskT);
    k_scan<<<N_IMGS, 64, 0, stream>>>(maskT, vcnt, keep, nkept);
    k_out<<<(N_IMGS * POST_K + 255) / 256, 256, 0, stream>>>((const float4*)boxes, keep, nkept, (float4*)d_out);
}

// Round 14
// 328.400 us; speedup vs baseline: 1.1276x; 1.1276x over previous
//
#include <hip/hip_runtime.h>
#include <stdint.h>

#define N_IMGS 8
#define NLVL 5
#define TOT 392832          // total anchors across levels
#define PRE_K 1000
#define POST_K 1000
#define KSEL 5000           // 5 levels * 1000
#define MASKW 79            // ceil(5000/64)
#define MROWS 5056          // KSEL padded to 79 full 64-row chunks
#define NCHUNK 79
#define LPAD 1024           // per-level padded list length
#define MSLOTS (NLVL * LPAD)

typedef unsigned long long u64;

struct Ptrs {
    const float* obj[5];
    const float* del[5];
    const float* anch;
};

__device__ __forceinline__ unsigned flipf(float f) {
    unsigned u = __float_as_uint(f);
    return (u & 0x80000000u) ? ~u : (u | 0x80000000u);
}

__device__ __forceinline__ void lvl_info(int t, int& l, int& off, int& W, int& H) {
    if (t < 294912)      { l = 0; off = 0;      W = 384; H = 256; }
    else if (t < 368640) { l = 1; off = 294912; W = 192; H = 128; }
    else if (t < 387072) { l = 2; off = 368640; W = 96;  H = 64;  }
    else if (t < 391680) { l = 3; off = 387072; W = 48;  H = 32;  }
    else                 { l = 4; off = 391680; W = 24;  H = 16;  }
}

// Decode one proposal exactly as the reference (f32, no FMA contraction).
__device__ void decode_one(const Ptrs& P, int n, int t, float bx[4], bool& valid, int& lvl) {
#pragma clang fp contract(off)
    int l, off, W, H;
    lvl_info(t, l, off, W, H);
    lvl = l;
    int i = t - off;
    int a = i % 3;
    int p = i / 3;
    int y = p / W, x = p - y * W;
    const float* D = P.del[l];
    size_t plane = (size_t)W * H;
    size_t base = ((size_t)n * 12 + (size_t)a * 4) * plane + (size_t)y * W + x;
    float dx = D[base];
    float dy = D[base + plane];
    float dw = D[base + 2 * plane];
    float dh = D[base + 3 * plane];
    const float* an = P.anch + (size_t)t * 4;
    float a0 = an[0], a1 = an[1], a2 = an[2], a3 = an[3];
    float wa = a2 - a0, ha = a3 - a1;
    float cxa = a0 + 0.5f * wa, cya = a1 + 0.5f * ha;
    const float CLIP = 4.135166556742356f;  // log(1000/16) rounded to f32
    dw = fminf(dw, CLIP);
    dh = fminf(dh, CLIP);
    float cx = dx * wa + cxa;
    float cy = dy * ha + cya;
    float pw = expf(dw) * wa;
    float ph = expf(dh) * ha;
    float x1 = cx - 0.5f * pw, y1 = cy - 0.5f * ph;
    float x2 = cx + 0.5f * pw, y2 = cy + 0.5f * ph;
    x1 = fminf(fmaxf(x1, 0.f), 1536.f);
    x2 = fminf(fmaxf(x2, 0.f), 1536.f);
    y1 = fminf(fmaxf(y1, 0.f), 1024.f);
    y2 = fminf(fmaxf(y2, 0.f), 1024.f);
    bx[0] = x1; bx[1] = y1; bx[2] = x2; bx[3] = y2;
    valid = ((x2 - x1) >= 1e-3f) && ((y2 - y1) >= 1e-3f);
}

__global__ void k_zero_out(float* out, int n) {
    int i = blockIdx.x * blockDim.x + threadIdx.x;
    if (i < n) out[i] = 0.f;
}

// Flatten objectness into (h,w,a) order per level, store order-flipped bits.
// Also initializes vcnt (block 0) — must run before k_mergedec.
__global__ void k_scores(Ptrs P, unsigned* scores, int* vcnt) {
    if (blockIdx.x == 0 && threadIdx.x < N_IMGS) vcnt[threadIdx.x] = KSEL;
    int idx = blockIdx.x * blockDim.x + threadIdx.x;
    if (idx >= N_IMGS * TOT) return;
    int n = idx / TOT, t = idx - n * TOT;
    int l, off, W, H;
    lvl_info(t, l, off, W, H);
    int i = t - off;
    int a = i % 3;
    int p = i / 3;
    int y = p / W, x = p - y * W;
    const float* O = P.obj[l];
    float v = O[(((size_t)n * 3 + a) * H + y) * (size_t)W + x];
    scores[idx] = flipf(v);
}

// Exact top-1000 per (image, level), lax.top_k tie semantics (score desc, index asc).
#define HCOPY 4100          // 4096 bins + 4 pad (bank decorrelation between copies)
#define CANDMAX 4096
__global__ __launch_bounds__(1024) void k_select(const unsigned* scores, uint2* sel) {
    int task = blockIdx.x;
    int n = task / 5, l = task % 5;
    int off, len;
    switch (l) {
        case 0: off = 0;      len = 294912; break;
        case 1: off = 294912; len = 73728;  break;
        case 2: off = 368640; len = 18432;  break;
        case 3: off = 387072; len = 4608;   break;
        default: off = 391680; len = 1152;  break;
    }
    const unsigned* S = scores + (size_t)n * TOT + off;
    const uint4* S4 = (const uint4*)S;
    int len4 = len >> 2;
    int t = threadIdx.x;

    __shared__ __align__(16) char smem[2 * HCOPY * 4];   // hist, later reused as cand
    unsigned* hist = (unsigned*)smem;
    unsigned long long* cand = (unsigned long long*)smem;
    __shared__ unsigned suf[1024];
    __shared__ unsigned sh_pivot, sh_krem;
    __shared__ int sh_ngt, sh_nc;

    // zero both hist copies
    for (int i = t; i < 2 * HCOPY; i += 1024) hist[i] = 0u;
    __syncthreads();

    // 12-bit histogram, copy = t&1
    unsigned* myh = hist + (t & 1) * HCOPY;
    for (int i = t; i < len4; i += 1024) {
        uint4 v = S4[i];
        atomicAdd(&myh[v.x >> 20], 1u);
        atomicAdd(&myh[v.y >> 20], 1u);
        atomicAdd(&myh[v.z >> 20], 1u);
        atomicAdd(&myh[v.w >> 20], 1u);
    }
    __syncthreads();
    // reduce copies
    for (int i = t; i < 4096; i += 1024) hist[i] += hist[HCOPY + i];
    __syncthreads();
    // per-group sums (4 bins/thread), inclusive suffix scan
    suf[t] = hist[4 * t] + hist[4 * t + 1] + hist[4 * t + 2] + hist[4 * t + 3];
    for (int d = 1; d < 1024; d <<= 1) {
        __syncthreads();
        unsigned v = (t + d < 1024) ? suf[t + d] : 0u;
        __syncthreads();
        suf[t] += v;
    }
    __syncthreads();
    // boundary group: suf[t] >= K, suf[t+1] < K
    unsigned above = (t == 1023) ? 0u : suf[t + 1];
    if (suf[t] >= PRE_K && above < PRE_K) {
        int b = 4 * t + 3;
        unsigned c = above;
        while (c + hist[b] < PRE_K) { c += hist[b]; --b; }
        sh_pivot = (unsigned)b;
        sh_krem = PRE_K - c;          // how many to take from pivot bin
        sh_ngt = 0; sh_nc = 0;
    }
    __syncthreads();
    unsigned pivot = sh_pivot;
    int krem = (int)sh_krem;
    __syncthreads();   // hist no longer needed; smem becomes cand

    // compact pass
    uint2* out = sel + (size_t)task * PRE_K;
    for (int i = t; i < len4; i += 1024) {
        uint4 v4 = S4[i];
        unsigned vv[4] = {v4.x, v4.y, v4.z, v4.w};
#pragma unroll
        for (int q = 0; q < 4; ++q) {
            unsigned v = vv[q];
            unsigned b = v >> 20;
            if (b > pivot) {
                int slot = atomicAdd(&sh_ngt, 1);
                out[slot] = make_uint2(v, (unsigned)(off + 4 * i + q));
            } else if (b == pivot) {
                int c = atomicAdd(&sh_nc, 1);
                if (c < CANDMAX)
                    cand[c] = ((unsigned long long)v << 32) | (unsigned)(off + 4 * i + q);
            }
        }
    }
    __syncthreads();
    int C = min(sh_nc, CANDMAX);
    int nbase = sh_ngt;               // == PRE_K - krem
    // exact rank among pivot-bin candidates (uniform j-loop -> LDS broadcast reads)
    for (int i = t; i < C; i += 1024) {
        unsigned long long a = cand[i];
        unsigned vi = (unsigned)(a >> 32), xi = (unsigned)a;
        int rank = 0;
        for (int j = 0; j < C; ++j) {
            unsigned long long bj = cand[j];
            unsigned vj = (unsigned)(bj >> 32), xj = (unsigned)bj;
            rank += (vj > vi) || (vj == vi && xj < xi);
        }
        if (rank < krem) out[nbase + rank] = make_uint2(vi, xi);
    }
}

// Fused key-build + per-(image,level) bitonic sort of 1024-padded list.
// Key: ascending order == (score desc, concat position asc); invalid -> tail.
__global__ __launch_bounds__(1024) void k_sort1(Ptrs P, const uint2* sel, u64* keys2) {
    __shared__ u64 s[LPAD];
    int task = blockIdx.x;          // n*5 + l
    int n = task / 5;
    int t = threadIdx.x;
    u64 key = ~0ull;
    if (t < PRE_K) {
        uint2 sv = sel[(size_t)task * PRE_K + t];
        float bx[4]; bool valid; int lv;
        decode_one(P, n, (int)sv.y, bx, valid, lv);
        key = valid ? (((u64)(~sv.x) << 32) | (u64)sv.y)
                    : (0xFFFFFFFF00000000ull | (u64)sv.y);
    }
    s[t] = key;
    for (int k = 2; k <= LPAD; k <<= 1) {
        for (int j = k >> 1; j > 0; j >>= 1) {
            __syncthreads();
            int ixj = t ^ j;
            if (ixj > t) {
                u64 a = s[t], b = s[ixj];
                bool asc = ((t & k) == 0);
                if (asc ? (a > b) : (a < b)) { s[t] = b; s[ixj] = a; }
            }
        }
    }
    __syncthreads();
    keys2[(size_t)task * LPAD + t] = s[t];
}

// Fused stable 5-way merge-by-rank + decode + scatter. Rank = own position +
// per-other-list binary-search count (<= for lists with smaller index, < else).
// Real keys are unique and < pad ~0ull -> bijection onto ranks 0..4999.
__global__ void k_mergedec(Ptrs P, const u64* keys2,
                           float4* boxes, float4* nboxes, int* vcnt) {
    int idx = blockIdx.x * blockDim.x + threadIdx.x;
    if (idx >= N_IMGS * MSLOTS) return;
    int n = idx / MSLOTS, slot = idx - n * MSLOTS;
    int l = slot >> 10, p = slot & (LPAD - 1);
    const u64* base = keys2 + (size_t)n * MSLOTS;
    u64 key = base[(size_t)l * LPAD + p];
    if (key == ~0ull) return;       // pad slot
    int rank = p;
#pragma unroll
    for (int m = 0; m < NLVL; ++m) {
        if (m == l) continue;
        const u64* L = base + (size_t)m * LPAD;
        bool le = (m < l);
        int lo = 0, hi = LPAD;
        while (lo < hi) {
            int mid = (lo + hi) >> 1;
            u64 v = L[mid];
            bool take = le ? (v <= key) : (v < key);
            if (take) lo = mid + 1; else hi = mid;
        }
        rank += lo;
    }
    if (rank >= KSEL) return;       // safety (unreachable for real keys)
    int oidx = n * KSEL + rank;
    if ((key >> 32) == 0xFFFFFFFFull) {
        boxes[oidx] = make_float4(0.f, 0.f, 0.f, 0.f);
        nboxes[oidx] = make_float4(0.f, 0.f, 0.f, 0.f);
        atomicMin(&vcnt[n], rank);
        return;
    }
    int t = (int)(key & 0xFFFFFFFFull);
    float bx[4]; bool valid; int lv;
    decode_one(P, n, t, bx, valid, lv);
    boxes[oidx] = make_float4(bx[0], bx[1], bx[2], bx[3]);
    float offv = (float)lv * 1537.0f;   // (max(H,W)+1) * level
    nboxes[oidx] = make_float4(bx[0] + offv, bx[1] + offv, bx[2] + offv, bx[3] + offv);
}

// Suppression bitmask, ballot form, 2 col-blocks per wave.
// Lanes = cols (register-resident), rounds = rows (5 readlane broadcasts
// amortized over 128 pairs). Exact branchless predicate: RN(inter/uni) > 0.7f
// <=> (double)inter >= MID * (double)uni with MID = midpoint(0.7f, nextup) =
// 0x1.666667p-1 (tie rounds to even = nextup, hence >=; both sides exact in
// f64: 24-bit x 25-bit mantissa <= 49 bits). uni==0 only for zero-area
// (invalid) boxes whose mask bits the scan never consumes.
// Diagonal/col masks applied on the wave-uniform word (SALU).
// TRANSPOSED layout: maskT[(n*MASKW + cword)*MROWS + r]; upper halves only.
__device__ __forceinline__ float rdlane(float v, int src) {
    return __int_as_float(__builtin_amdgcn_readlane(__float_as_int(v), src));
}
__global__ __launch_bounds__(64) void k_mask(const float4* __restrict__ nboxes,
                                             u64* __restrict__ maskT) {
#pragma clang fp contract(off)
    int rb = blockIdx.x, cs = blockIdx.y, n = blockIdx.z;
    int cb0 = cs * 2, cb1 = cb0 + 1;
    if (cb1 < rb) return;           // whole superblock below diagonal
    int lane = threadIdx.x;
    int r0 = rb * 64;
    const float4 z4 = make_float4(0.f, 0.f, 0.f, 0.f);
    const float4* B = nboxes + (size_t)n * KSEL;
    float4 rbx = (r0 + lane < KSEL) ? B[r0 + lane] : z4;
    float areaR = (rbx.z - rbx.x) * (rbx.w - rbx.y);
    float4 cA = (cb0 * 64 + lane < KSEL) ? B[cb0 * 64 + lane] : z4;
    float4 cB = (cb1 * 64 + lane < KSEL && cb1 < MASKW) ? B[cb1 * 64 + lane] : z4;
    float aCA = (cA.z - cA.x) * (cA.w - cA.y);
    float aCB = (cB.z - cB.x) * (cB.w - cB.y);
    u64 cmA = __ballot(cb0 * 64 + lane < KSEL);
    u64 cmB = __ballot(cb1 * 64 + lane < KSEL && cb1 < MASKW);
    const double MID = 0x1.666667p-1;
    u64 wA = 0ull, wB = 0ull;
#pragma unroll 4
    for (int rr = 0; rr < 64; ++rr) {
        float rx1 = rdlane(rbx.x, rr), ry1 = rdlane(rbx.y, rr);
        float rx2 = rdlane(rbx.z, rr), ry2 = rdlane(rbx.w, rr);
        float aR  = rdlane(areaR, rr);
        // half A
        float wvA = fmaxf(fminf(rx2, cA.z) - fmaxf(rx1, cA.x), 0.f);
        float hvA = fmaxf(fminf(ry2, cA.w) - fmaxf(ry1, cA.y), 0.f);
        float inA = wvA * hvA;
        float unA = (aR + aCA) - inA;
        bool supA = (double)inA >= MID * (double)unA;
        // half B
        float wvB = fmaxf(fminf(rx2, cB.z) - fmaxf(rx1, cB.x), 0.f);
        float hvB = fmaxf(fminf(ry2, cB.w) - fmaxf(ry1, cB.y), 0.f);
        float inB = wvB * hvB;
        float unB = (aR + aCB) - inB;
        bool supB = (double)inB >= MID * (double)unB;
        u64 a = __ballot((int)supA) & cmA;
        u64 b = __ballot((int)supB) & cmB;
        u64 dm = ~((2ull << rr) - 1ull);    // bits lane > rr (0 at rr=63)
        if (rb == cb0) a &= dm;
        if (rb == cb1) b &= dm;
        wA = (lane == rr) ? a : wA;
        wB = (lane == rr) ? b : wB;
    }
    if (r0 + lane < KSEL) {
        if (cb0 >= rb)
            maskT[((size_t)n * MASKW + cb0) * MROWS + r0 + lane] = wA;
        if (cb1 < MASKW)
            maskT[((size_t)n * MASKW + cb1) * MROWS + r0 + lane] = wB;
    }
}

__device__ __forceinline__ u64 bcast64(u64 v, int src) {
    unsigned lo = (unsigned)__builtin_amdgcn_readlane((int)(unsigned)v, src);
    unsigned hi = (unsigned)__builtin_amdgcn_readlane((int)(unsigned)(v >> 32), src);
    return ((u64)hi << 32) | (u64)lo;
}

// Wave64 OR-reduce via DPP (AMD GCN canonical sequence), result in lane 63.
__device__ __forceinline__ unsigned or_red_dpp(unsigned v) {
    v |= (unsigned)__builtin_amdgcn_update_dpp(0, (int)v, 0x111, 0xf, 0xf, true);  // row_shr:1
    v |= (unsigned)__builtin_amdgcn_update_dpp(0, (int)v, 0x112, 0xf, 0xf, true);  // row_shr:2
    v |= (unsigned)__builtin_amdgcn_update_dpp(0, (int)v, 0x114, 0xf, 0xf, true);  // row_shr:4
    v |= (unsigned)__builtin_amdgcn_update_dpp(0, (int)v, 0x118, 0xf, 0xf, true);  // row_shr:8
    v |= (unsigned)__builtin_amdgcn_update_dpp(0, (int)v, 0x142, 0xa, 0xf, false); // row_bcast:15
    v |= (unsigned)__builtin_amdgcn_update_dpp(0, (int)v, 0x143, 0xc, 0xf, false); // row_bcast:31
    return v;
}

// Single-wave greedy NMS scan, fully software-pipelined (see round 8 notes).
__global__ __launch_bounds__(64, 1) void k_scan(const u64* maskT, const int* vcnt,
                                                int* keep, int* nkept) {
    __shared__ int keep_lds[1024];
    int n = blockIdx.x, lane = threadIdx.x;
    int V = vcnt[n];
    const u64* MT = maskT + (size_t)n * MASKW * MROWS;

    for (int i = lane; i < 1024; i += 64) keep_lds[i] = 0;   // single wave: no barrier

    int cnt = 0, cntprev = 0;
    u64 keptprev = 0ull;
    bool full = false;
    int nchunks = (V + 63) >> 6;

    u64 bulk[16];
#pragma unroll
    for (int q = 0; q < 16; ++q) bulk[q] = 0ull;
    u64 wc = MT[lane];      // word 0 of chunk 0 rows
    u64 nc = 0ull;

    for (int c = 0; c < nchunks && !full; ++c) {
        // ---- assemble suppression word c from pipelined inputs ----
        u64 part = 0ull;
#pragma unroll
        for (int q = 0; q < 16; ++q)
            part |= (q * 64 + lane < cntprev) ? bulk[q] : 0ull;
        part |= ((keptprev >> lane) & 1ull) ? nc : 0ull;

        unsigned plo = or_red_dpp((unsigned)part);
        unsigned phi = or_red_dpp((unsigned)(part >> 32));
        u64 cur = ((u64)(unsigned)__builtin_amdgcn_readlane((int)phi, 63) << 32)
                | (u64)(unsigned)__builtin_amdgcn_readlane((int)plo, 63);

        // ---- issue generation c+1 ----
        int cntNow = cnt;
        int colN = (c + 1 < NCHUNK) ? (c + 1) : (NCHUNK - 1);
        const u64* colNp = MT + (size_t)colN * MROWS;
        {
            int kr[16];
#pragma unroll
            for (int q = 0; q < 16; ++q) kr[q] = keep_lds[q * 64 + lane];
#pragma unroll
            for (int q = 0; q < 16; ++q) bulk[q] = colNp[kr[q]];
        }
        u64 nc_next = colNp[(size_t)c * 64 + lane];
        u64 wc_next = colNp[(size_t)colN * 64 + lane];

        // ---- serial chain on chunk c ----
        int base = c * 64;
        int jmax = V - base; if (jmax > 64) jmax = 64;
        u64 avail = ~cur;
        if (jmax < 64) avail &= (1ull << jmax) - 1ull;
        while (avail) {
            int j = __builtin_ctzll(avail);
            if (lane == 0) keep_lds[cnt] = base + j;
            ++cnt;
            if (cnt == POST_K) { full = true; break; }
            u64 wcj = bcast64(wc, j);
            avail &= avail - 1;
            avail &= ~wcj;
        }
        keptprev = 0ull;
        for (int i = cntNow + (int)lane; i < cnt; i += 64) {
            int r = keep_lds[i];
            keptprev |= 1ull << (r - base);
        }
        {
            unsigned klo = or_red_dpp((unsigned)keptprev);
            unsigned khi = or_red_dpp((unsigned)(keptprev >> 32));
            keptprev = ((u64)(unsigned)__builtin_amdgcn_readlane((int)khi, 63) << 32)
                     | (u64)(unsigned)__builtin_amdgcn_readlane((int)klo, 63);
        }
        cntprev = cntNow;
        wc = wc_next;
        nc = nc_next;
    }

    for (int i = lane; i < cnt; i += 64) keep[n * POST_K + i] = keep_lds[i];
    if (lane == 0) nkept[n] = cnt;
}

__global__ void k_out(const float4* boxes, const int* keep, const int* nkept, float4* out) {
    int idx = blockIdx.x * blockDim.x + threadIdx.x;
    if (idx >= N_IMGS * POST_K) return;
    int n = idx / POST_K, k = idx - n * POST_K;
    float4 v = make_float4(0.f, 0.f, 0.f, 0.f);
    if (k < nkept[n]) v = boxes[(size_t)n * KSEL + keep[n * POST_K + k]];
    out[idx] = v;
}

extern "C" void kernel_launch(void* const* d_in, const int* in_sizes, int n_in,
                              void* d_out, int out_size, void* d_ws, size_t ws_size,
                              hipStream_t stream) {
    // dict order: obj0, delta0, obj1, delta1, ..., obj4, delta4, anchors
    Ptrs P;
    for (int l = 0; l < 5; ++l) {
        P.obj[l] = (const float*)d_in[2 * l];
        P.del[l] = (const float*)d_in[2 * l + 1];
    }
    P.anch = (const float*)d_in[10];

    // workspace carve
    size_t o = 0;
    auto alloc = [&](size_t bytes) {
        size_t cur = o;
        o = (o + bytes + 255) & ~(size_t)255;
        return cur;
    };
    size_t off_scores = alloc((size_t)N_IMGS * TOT * 4);
    size_t off_sel    = alloc((size_t)N_IMGS * KSEL * 8);
    size_t off_keys2  = alloc((size_t)N_IMGS * MSLOTS * 8);
    size_t off_boxes  = alloc((size_t)N_IMGS * KSEL * 16);
    size_t off_nbox   = alloc((size_t)N_IMGS * KSEL * 16);
    size_t off_mask   = alloc((size_t)N_IMGS * MASKW * MROWS * 8);
    size_t off_vcnt   = alloc(N_IMGS * 4);
    size_t off_keep   = alloc((size_t)N_IMGS * POST_K * 4);
    size_t off_nkept  = alloc(N_IMGS * 4);

    float* out = (float*)d_out;
    if (o > ws_size) {  // workspace too small: emit zeros (visible failure, no crash)
        k_zero_out<<<(out_size + 255) / 256, 256, 0, stream>>>(out, out_size);
        return;
    }

    char* w = (char*)d_ws;
    unsigned* scores = (unsigned*)(w + off_scores);
    uint2* sel       = (uint2*)(w + off_sel);
    u64* keys2       = (u64*)(w + off_keys2);
    float4* boxes    = (float4*)(w + off_boxes);
    float4* nboxes   = (float4*)(w + off_nbox);
    u64* maskT       = (u64*)(w + off_mask);
    int* vcnt        = (int*)(w + off_vcnt);
    int* keep        = (int*)(w + off_keep);
    int* nkept       = (int*)(w + off_nkept);

    k_scores<<<(N_IMGS * TOT + 255) / 256, 256, 0, stream>>>(P, scores, vcnt);
    k_select<<<N_IMGS * NLVL, 1024, 0, stream>>>(scores, sel);
    k_sort1<<<N_IMGS * NLVL, 1024, 0, stream>>>(P, sel, keys2);
    k_mergedec<<<(N_IMGS * MSLOTS + 255) / 256, 256, 0, stream>>>(P, keys2, boxes, nboxes, vcnt);
    k_mask<<<dim3(NCHUNK, (MASKW + 1) / 2, N_IMGS), 64, 0, stream>>>(nboxes, maskT);
    k_scan<<<N_IMGS, 64, 0, stream>>>(maskT, vcnt, keep, nkept);
    k_out<<<(N_IMGS * POST_K + 255) / 256, 256, 0, stream>>>((const float4*)boxes, keep, nkept, (float4*)d_out);
}